// Round 1
// baseline (506.237 us; speedup 1.0000x reference)
//
#include <hip/hip_runtime.h>
#include <cstdint>
#include <cstddef>

// Problem constants: B=4, T=2048, C=1024, H=16, D=64, tokens M=8192.
#define MTOK 8192
#define CDIM 1024

typedef __bf16 bf16x8 __attribute__((ext_vector_type(8)));
typedef float  f32x4  __attribute__((ext_vector_type(4)));

__device__ __forceinline__ uint16_t f2bf(float f) {
    uint32_t u = __builtin_bit_cast(uint32_t, f);
    uint32_t r = (u + 0x7fffu + ((u >> 16) & 1u)) >> 16;  // RNE
    return (uint16_t)r;
}

__device__ __forceinline__ void gload_lds16(const uint16_t* g, uint16_t* l) {
    // async global->LDS, 16B/lane; LDS dest is wave-uniform base + lane*16
    __builtin_amdgcn_global_load_lds((const __attribute__((address_space(1))) void*)g,
                                     (__attribute__((address_space(3))) void*)l, 16, 0, 0);
}

// ---------------------------------------------------------------- prep kernels
__global__ __launch_bounds__(256) void convert_x_kernel(const float* __restrict__ x,
                                                        uint16_t* __restrict__ xb, int n) {
    int i = (blockIdx.x * 256 + threadIdx.x) * 4;
    int stride = gridDim.x * 256 * 4;
    for (; i < n; i += stride) {
        float4 v = *reinterpret_cast<const float4*>(x + i);
        uint64_t pk = (uint64_t)f2bf(v.x) | ((uint64_t)f2bf(v.y) << 16) |
                      ((uint64_t)f2bf(v.z) << 32) | ((uint64_t)f2bf(v.w) << 48);
        *reinterpret_cast<uint64_t*>(xb + i) = pk;
    }
}

// W[k][n] f32  ->  Wt[n][k] bf16   (4 weights via blockIdx.z)
__global__ __launch_bounds__(256) void transpose_w_kernel(const float* __restrict__ W0,
                                                          const float* __restrict__ W1,
                                                          const float* __restrict__ W2,
                                                          const float* __restrict__ W3,
                                                          uint16_t* __restrict__ Wt) {
    __shared__ float tile[32][33];
    const float* W = blockIdx.z == 0 ? W0 : blockIdx.z == 1 ? W1 : blockIdx.z == 2 ? W2 : W3;
    uint16_t* out = Wt + (size_t)blockIdx.z * 1024 * 1024;
    int k0 = blockIdx.y * 32, n0 = blockIdx.x * 32;
    int tx = threadIdx.x, ty = threadIdx.y;  // block (32,8)
#pragma unroll
    for (int i = 0; i < 4; i++) tile[ty * 4 + i][tx] = W[(size_t)(k0 + ty * 4 + i) * 1024 + n0 + tx];
    __syncthreads();
#pragma unroll
    for (int i = 0; i < 4; i++) out[(size_t)(n0 + ty * 4 + i) * 1024 + k0 + tx] = f2bf(tile[tx][ty * 4 + i]);
}

// ---------------------------------------------------------------- GEMM mainloop
// C[128x128] tile of A[M][1024](bf16, row-major) @ Wt[N][1024](bf16, row-major=B^T).
// 256 threads = 4 waves (2x2 of 64x64). m97 structure: global_load_lds w16, BK=32.
__device__ __forceinline__ void gemm128_mainloop(const uint16_t* __restrict__ A,
                                                 const uint16_t* __restrict__ Wt,
                                                 int m0, int n0,
                                                 uint16_t* Als, uint16_t* Bls,
                                                 f32x4 acc[4][4]) {
    const int tid = threadIdx.x;
    const int wave = tid >> 6, lane = tid & 63;
    const int g = lane >> 4, c = lane & 15;
    const int wr = wave >> 1, wc = wave & 1;
    const int r = tid >> 2, cc = (tid & 3) * 8;
#pragma unroll
    for (int mi = 0; mi < 4; mi++)
#pragma unroll
        for (int ni = 0; ni < 4; ni++) acc[mi][ni] = f32x4{0.f, 0.f, 0.f, 0.f};

    for (int k0 = 0; k0 < 1024; k0 += 32) {
        __syncthreads();  // previous iteration's ds_reads done before overwrite
        gload_lds16(A + (size_t)(m0 + r) * 1024 + k0 + cc, Als + wave * 512);
        gload_lds16(A + (size_t)(m0 + 64 + r) * 1024 + k0 + cc, Als + 2048 + wave * 512);
        gload_lds16(Wt + (size_t)(n0 + r) * 1024 + k0 + cc, Bls + wave * 512);
        gload_lds16(Wt + (size_t)(n0 + 64 + r) * 1024 + k0 + cc, Bls + 2048 + wave * 512);
        __syncthreads();  // staging complete (syncthreads drains vmcnt)
        bf16x8 af[4], bf[4];
#pragma unroll
        for (int mi = 0; mi < 4; mi++)
            af[mi] = *reinterpret_cast<const bf16x8*>(Als + (wr * 64 + mi * 16 + c) * 32 + g * 8);
#pragma unroll
        for (int ni = 0; ni < 4; ni++)
            bf[ni] = *reinterpret_cast<const bf16x8*>(Bls + (wc * 64 + ni * 16 + c) * 32 + g * 8);
#pragma unroll
        for (int mi = 0; mi < 4; mi++)
#pragma unroll
            for (int ni = 0; ni < 4; ni++)
                acc[mi][ni] = __builtin_amdgcn_mfma_f32_16x16x32_bf16(af[mi], bf[ni], acc[mi][ni], 0, 0, 0);
    }
}

// ---------------------------------------------------------------- QKV projection
// z=0: Q = (x@Wq+bq)*0.125 -> [B,H,T,D] bf16   (attention scale folded in)
// z=1: K = x@Wk+bk        -> [B,H,T,D] bf16
// z=2: V = x@Wv+bv        -> [B,H,D,T] bf16    (transposed for PV B-frag reads)
__global__ __launch_bounds__(256) void qkv_gemm_kernel(const uint16_t* __restrict__ xb,
                                                       const uint16_t* __restrict__ WtAll,
                                                       const float* __restrict__ bq,
                                                       const float* __restrict__ bk,
                                                       const float* __restrict__ bv,
                                                       uint16_t* __restrict__ Qg,
                                                       uint16_t* __restrict__ Kg,
                                                       uint16_t* __restrict__ Vtg) {
    __shared__ uint16_t Als[4096], Bls[4096];
    const int z = blockIdx.z;
    const uint16_t* Wt = WtAll + (size_t)z * 1024 * 1024;
    const float* bias = z == 0 ? bq : z == 1 ? bk : bv;
    const int m0 = blockIdx.y * 128, n0 = blockIdx.x * 128;
    f32x4 acc[4][4];
    gemm128_mainloop(xb, Wt, m0, n0, Als, Bls, acc);

    const int tid = threadIdx.x, wave = tid >> 6, lane = tid & 63;
    const int g = lane >> 4, c = lane & 15;
    const int wr = wave >> 1, wc = wave & 1;
#pragma unroll
    for (int ni = 0; ni < 4; ni++) {
        int n = n0 + wc * 64 + ni * 16 + c;
        float bb = bias[n];
        int h = n >> 6, d = n & 63;
#pragma unroll
        for (int mi = 0; mi < 4; mi++)
#pragma unroll
            for (int j = 0; j < 4; j++) {
                int m = m0 + wr * 64 + mi * 16 + g * 4 + j;
                int b = m >> 11, t = m & 2047;
                float v = acc[mi][ni][j] + bb;
                size_t bhOff = (size_t)(b * 16 + h) * 131072;
                if (z == 0)      Qg[bhOff + (size_t)t * 64 + d] = f2bf(v * 0.125f);
                else if (z == 1) Kg[bhOff + (size_t)t * 64 + d] = f2bf(v);
                else             Vtg[bhOff + (size_t)d * 2048 + t] = f2bf(v);
            }
    }
}

// ---------------------------------------------------------------- flash attention
// grid (16 q-tiles, 64 bh); 256 threads = 4 waves, each wave owns 32 q rows.
__global__ __launch_bounds__(256) void attn_kernel(const uint16_t* __restrict__ Qg,
                                                   const uint16_t* __restrict__ Kg,
                                                   const uint16_t* __restrict__ Vtg,
                                                   uint16_t* __restrict__ Oatt) {
    const int bh = blockIdx.y;
    const int q0 = blockIdx.x * 128;
    const int tid = threadIdx.x, wave = tid >> 6, lane = tid & 63;
    const int g = lane >> 4, c = lane & 15;
    const int qw = q0 + wave * 32;
    const uint16_t* Qb = Qg + (size_t)bh * 131072;
    const uint16_t* Kb = Kg + (size_t)bh * 131072;
    const uint16_t* Vb = Vtg + (size_t)bh * 131072;

    __shared__ uint16_t Pl[4][32][80];  // per-wave P scratch; 160B row stride (16B-aligned, conflict-light)

    bf16x8 qf[2][2];
#pragma unroll
    for (int qi = 0; qi < 2; qi++)
#pragma unroll
        for (int dh = 0; dh < 2; dh++)
            qf[qi][dh] = *reinterpret_cast<const bf16x8*>(Qb + (size_t)(qw + qi * 16 + c) * 64 + dh * 32 + g * 8);

    f32x4 o[2][4];
    float mrow[2][4], lrow[2][4];
#pragma unroll
    for (int qi = 0; qi < 2; qi++) {
#pragma unroll
        for (int dt = 0; dt < 4; dt++) o[qi][dt] = f32x4{0.f, 0.f, 0.f, 0.f};
#pragma unroll
        for (int j = 0; j < 4; j++) { mrow[qi][j] = -__builtin_inff(); lrow[qi][j] = 0.f; }
    }

    for (int kv = 0; kv < 2048; kv += 64) {
        // --- S = Q K^T (Q pre-scaled by 1/8). B-frag of K^T == contiguous row read of K.
        bf16x8 kf[4][2];
#pragma unroll
        for (int kt = 0; kt < 4; kt++)
#pragma unroll
            for (int dh = 0; dh < 2; dh++)
                kf[kt][dh] = *reinterpret_cast<const bf16x8*>(Kb + (size_t)(kv + kt * 16 + c) * 64 + dh * 32 + g * 8);
        f32x4 s[2][4];
#pragma unroll
        for (int qi = 0; qi < 2; qi++)
#pragma unroll
            for (int kt = 0; kt < 4; kt++) {
                f32x4 acc = f32x4{0.f, 0.f, 0.f, 0.f};
                acc = __builtin_amdgcn_mfma_f32_16x16x32_bf16(qf[qi][0], kf[kt][0], acc, 0, 0, 0);
                acc = __builtin_amdgcn_mfma_f32_16x16x32_bf16(qf[qi][1], kf[kt][1], acc, 0, 0, 0);
                s[qi][kt] = acc;
            }
        // --- online softmax. S elem: row q = qi*16+g*4+j, col k = kv+kt*16+c.
        // Row-reduce = reduce across the 16 lanes sharing g (xor masks 1,2,4,8).
#pragma unroll
        for (int qi = 0; qi < 2; qi++) {
#pragma unroll
            for (int j = 0; j < 4; j++) {
                float v = fmaxf(fmaxf(s[qi][0][j], s[qi][1][j]), fmaxf(s[qi][2][j], s[qi][3][j]));
                v = fmaxf(v, __shfl_xor(v, 1));
                v = fmaxf(v, __shfl_xor(v, 2));
                v = fmaxf(v, __shfl_xor(v, 4));
                v = fmaxf(v, __shfl_xor(v, 8));
                float nm = fmaxf(mrow[qi][j], v);
                float al = __expf(mrow[qi][j] - nm);
                mrow[qi][j] = nm;
                float rs = 0.f;
#pragma unroll
                for (int kt = 0; kt < 4; kt++) {
                    float p = __expf(s[qi][kt][j] - nm);
                    s[qi][kt][j] = p;
                    rs += p;
                }
                rs += __shfl_xor(rs, 1);
                rs += __shfl_xor(rs, 2);
                rs += __shfl_xor(rs, 4);
                rs += __shfl_xor(rs, 8);
                lrow[qi][j] = lrow[qi][j] * al + rs;
#pragma unroll
                for (int dt = 0; dt < 4; dt++) o[qi][dt][j] *= al;
            }
        }
        // --- P (S-layout) -> LDS -> A-frag layout. Per-wave private, no barrier needed.
#pragma unroll
        for (int qi = 0; qi < 2; qi++)
#pragma unroll
            for (int kt = 0; kt < 4; kt++)
#pragma unroll
                for (int j = 0; j < 4; j++)
                    Pl[wave][qi * 16 + g * 4 + j][kt * 16 + c] = f2bf(s[qi][kt][j]);
        // --- O += P V. B-frag of V == contiguous row read of Vt.
        bf16x8 vf[4][2];
#pragma unroll
        for (int dt = 0; dt < 4; dt++)
#pragma unroll
            for (int ks = 0; ks < 2; ks++)
                vf[dt][ks] = *reinterpret_cast<const bf16x8*>(Vb + (size_t)(dt * 16 + c) * 2048 + kv + ks * 32 + g * 8);
#pragma unroll
        for (int qi = 0; qi < 2; qi++)
#pragma unroll
            for (int ks = 0; ks < 2; ks++) {
                bf16x8 pf = *reinterpret_cast<const bf16x8*>(&Pl[wave][qi * 16 + c][ks * 32 + g * 8]);
#pragma unroll
                for (int dt = 0; dt < 4; dt++)
                    o[qi][dt] = __builtin_amdgcn_mfma_f32_16x16x32_bf16(pf, vf[dt][ks], o[qi][dt], 0, 0, 0);
            }
    }
    // --- epilogue: normalize by l, write bf16 token-major [M][C]
    const int b = bh >> 4, h = bh & 15;
#pragma unroll
    for (int qi = 0; qi < 2; qi++)
#pragma unroll
        for (int j = 0; j < 4; j++) {
            float inv = 1.0f / lrow[qi][j];
            int q = qw + qi * 16 + g * 4 + j;
#pragma unroll
            for (int dt = 0; dt < 4; dt++)
                Oatt[((size_t)(b * 2048 + q)) * 1024 + h * 64 + dt * 16 + c] = f2bf(o[qi][dt][j] * inv);
        }
}

// ---------------------------------------------------------------- output projection (f32 out)
__global__ __launch_bounds__(256) void out_gemm_kernel(const uint16_t* __restrict__ Oatt,
                                                       const uint16_t* __restrict__ WtO,
                                                       const float* __restrict__ bo,
                                                       float* __restrict__ out) {
    __shared__ uint16_t Als[4096], Bls[4096];
    const int m0 = blockIdx.y * 128, n0 = blockIdx.x * 128;
    f32x4 acc[4][4];
    gemm128_mainloop(Oatt, WtO, m0, n0, Als, Bls, acc);

    const int tid = threadIdx.x, wave = tid >> 6, lane = tid & 63;
    const int g = lane >> 4, c = lane & 15;
    const int wr = wave >> 1, wc = wave & 1;
#pragma unroll
    for (int ni = 0; ni < 4; ni++) {
        int n = n0 + wc * 64 + ni * 16 + c;
        float bb = bo[n];
#pragma unroll
        for (int mi = 0; mi < 4; mi++)
#pragma unroll
            for (int j = 0; j < 4; j++) {
                int m = m0 + wr * 64 + mi * 16 + g * 4 + j;
                out[(size_t)m * 1024 + n] = acc[mi][ni][j] + bb;
            }
    }
}

// ---------------------------------------------------------------- launch
extern "C" void kernel_launch(void* const* d_in, const int* in_sizes, int n_in,
                              void* d_out, int out_size, void* d_ws, size_t ws_size,
                              hipStream_t stream) {
    const float* x  = (const float*)d_in[0];
    const float* Wq = (const float*)d_in[1];
    const float* bq = (const float*)d_in[2];
    const float* Wk = (const float*)d_in[3];
    const float* bk = (const float*)d_in[4];
    const float* Wv = (const float*)d_in[5];
    const float* bv = (const float*)d_in[6];
    const float* Wo = (const float*)d_in[7];
    const float* bo = (const float*)d_in[8];
    float* out = (float*)d_out;

    char* ws = (char*)d_ws;
    // ws layout (bytes): xb 16MB | Wt 8MB | Qg 16MB | Kg 16MB | Vtg 16MB ; Oatt aliases xb.
    uint16_t* xb   = (uint16_t*)(ws);
    uint16_t* Wt   = (uint16_t*)(ws + 16777216);
    uint16_t* Qg   = (uint16_t*)(ws + 25165824);
    uint16_t* Kg   = (uint16_t*)(ws + 41943040);
    uint16_t* Vtg  = (uint16_t*)(ws + 58720256);
    uint16_t* Oatt = (uint16_t*)(ws);  // reuse xb region (xb dead after qkv_gemm)

    convert_x_kernel<<<4096, 256, 0, stream>>>(x, xb, MTOK * CDIM);
    transpose_w_kernel<<<dim3(32, 32, 4), dim3(32, 8), 0, stream>>>(Wq, Wk, Wv, Wo, Wt);
    qkv_gemm_kernel<<<dim3(8, 64, 3), 256, 0, stream>>>(xb, Wt, bq, bk, bv, Qg, Kg, Vtg);
    attn_kernel<<<dim3(16, 64), 256, 0, stream>>>(Qg, Kg, Vtg, Oatt);
    out_gemm_kernel<<<dim3(8, 64), 256, 0, stream>>>(Oatt, Wt + (size_t)3 * 1048576, bo, out);
}

// Round 3
// 451.123 us; speedup vs baseline: 1.1222x; 1.1222x over previous
//
#include <hip/hip_runtime.h>
#include <cstdint>
#include <cstddef>

// Problem constants: B=4, T=2048, C=1024, H=16, D=64, tokens M=8192.
#define MTOK 8192
#define CDIM 1024

typedef __bf16 bf16x8 __attribute__((ext_vector_type(8)));
typedef float  f32x4  __attribute__((ext_vector_type(4)));
typedef float  f32x16 __attribute__((ext_vector_type(16)));
typedef uint32_t u32x4 __attribute__((ext_vector_type(4)));

// 1/sqrt(64) * log2(e): QK^T softmax done in exp2 domain.
#define QSCALE 0.18033688011112042f

__device__ __forceinline__ uint16_t f2bf(float f) {
    return __builtin_bit_cast(uint16_t, (__bf16)f);  // HW RNE cvt (don't hand-write; m240)
}
__device__ __forceinline__ uint32_t cvtpk(float lo, float hi) {
    return (uint32_t)__builtin_bit_cast(uint16_t, (__bf16)lo) |
           ((uint32_t)__builtin_bit_cast(uint16_t, (__bf16)hi) << 16);
}

__device__ __forceinline__ void gload_lds16(const uint16_t* g, uint16_t* l) {
    __builtin_amdgcn_global_load_lds((const __attribute__((address_space(1))) void*)g,
                                     (__attribute__((address_space(3))) void*)l, 16, 0, 0);
}

// ---------------------------------------------------------------- prep kernels
__global__ __launch_bounds__(256) void convert_x_kernel(const float* __restrict__ x,
                                                        uint16_t* __restrict__ xb, int n) {
    int i = (blockIdx.x * 256 + threadIdx.x) * 4;
    int stride = gridDim.x * 256 * 4;
    for (; i < n; i += stride) {
        float4 v = *reinterpret_cast<const float4*>(x + i);
        uint64_t pk = (uint64_t)cvtpk(v.x, v.y) | ((uint64_t)cvtpk(v.z, v.w) << 32);
        *reinterpret_cast<uint64_t*>(xb + i) = pk;
    }
}

// W[k][n] f32  ->  Wt[n][k] bf16   (4 weights via blockIdx.z)
__global__ __launch_bounds__(256) void transpose_w_kernel(const float* __restrict__ W0,
                                                          const float* __restrict__ W1,
                                                          const float* __restrict__ W2,
                                                          const float* __restrict__ W3,
                                                          uint16_t* __restrict__ Wt) {
    __shared__ float tile[32][33];
    const float* W = blockIdx.z == 0 ? W0 : blockIdx.z == 1 ? W1 : blockIdx.z == 2 ? W2 : W3;
    uint16_t* out = Wt + (size_t)blockIdx.z * 1024 * 1024;
    int k0 = blockIdx.y * 32, n0 = blockIdx.x * 32;
    int tx = threadIdx.x, ty = threadIdx.y;  // block (32,8)
#pragma unroll
    for (int i = 0; i < 4; i++) tile[ty * 4 + i][tx] = W[(size_t)(k0 + ty * 4 + i) * 1024 + n0 + tx];
    __syncthreads();
#pragma unroll
    for (int i = 0; i < 4; i++) out[(size_t)(n0 + ty * 4 + i) * 1024 + k0 + tx] = f2bf(tile[tx][ty * 4 + i]);
}

// ---------------------------------------------------------------- GEMM mainloop
__device__ __forceinline__ void gemm128_mainloop(const uint16_t* __restrict__ A,
                                                 const uint16_t* __restrict__ Wt,
                                                 int m0, int n0,
                                                 uint16_t* Als, uint16_t* Bls,
                                                 f32x4 acc[4][4]) {
    const int tid = threadIdx.x;
    const int wave = tid >> 6, lane = tid & 63;
    const int g = lane >> 4, c = lane & 15;
    const int wr = wave >> 1, wc = wave & 1;
    const int r = tid >> 2, cc = (tid & 3) * 8;
#pragma unroll
    for (int mi = 0; mi < 4; mi++)
#pragma unroll
        for (int ni = 0; ni < 4; ni++) acc[mi][ni] = f32x4{0.f, 0.f, 0.f, 0.f};

    for (int k0 = 0; k0 < 1024; k0 += 32) {
        __syncthreads();
        gload_lds16(A + (size_t)(m0 + r) * 1024 + k0 + cc, Als + wave * 512);
        gload_lds16(A + (size_t)(m0 + 64 + r) * 1024 + k0 + cc, Als + 2048 + wave * 512);
        gload_lds16(Wt + (size_t)(n0 + r) * 1024 + k0 + cc, Bls + wave * 512);
        gload_lds16(Wt + (size_t)(n0 + 64 + r) * 1024 + k0 + cc, Bls + 2048 + wave * 512);
        __syncthreads();
        bf16x8 af[4], bf[4];
#pragma unroll
        for (int mi = 0; mi < 4; mi++)
            af[mi] = *reinterpret_cast<const bf16x8*>(Als + (wr * 64 + mi * 16 + c) * 32 + g * 8);
#pragma unroll
        for (int ni = 0; ni < 4; ni++)
            bf[ni] = *reinterpret_cast<const bf16x8*>(Bls + (wc * 64 + ni * 16 + c) * 32 + g * 8);
#pragma unroll
        for (int mi = 0; mi < 4; mi++)
#pragma unroll
            for (int ni = 0; ni < 4; ni++)
                acc[mi][ni] = __builtin_amdgcn_mfma_f32_16x16x32_bf16(af[mi], bf[ni], acc[mi][ni], 0, 0, 0);
    }
}

// ---------------------------------------------------------------- QKV projection
// z=0: Q = (x@Wq+bq)*QSCALE -> [B,H,T,D] bf16 (attn scale + log2e folded)
// z=1: K = x@Wk+bk          -> [B,H,T,D] bf16
// z=2: V = x@Wv+bv          -> [B,H,D,T] bf16 (transposed: PV/O^T A-frag reads)
__global__ __launch_bounds__(256) void qkv_gemm_kernel(const uint16_t* __restrict__ xb,
                                                       const uint16_t* __restrict__ WtAll,
                                                       const float* __restrict__ bq,
                                                       const float* __restrict__ bk,
                                                       const float* __restrict__ bv,
                                                       uint16_t* __restrict__ Qg,
                                                       uint16_t* __restrict__ Kg,
                                                       uint16_t* __restrict__ Vtg) {
    __shared__ uint16_t Als[4096], Bls[4096];
    const int z = blockIdx.z;
    const uint16_t* Wt = WtAll + (size_t)z * 1024 * 1024;
    const float* bias = z == 0 ? bq : z == 1 ? bk : bv;
    const int m0 = blockIdx.y * 128, n0 = blockIdx.x * 128;
    f32x4 acc[4][4];
    gemm128_mainloop(xb, Wt, m0, n0, Als, Bls, acc);

    const int tid = threadIdx.x, wave = tid >> 6, lane = tid & 63;
    const int g = lane >> 4, c = lane & 15;
    const int wr = wave >> 1, wc = wave & 1;
#pragma unroll
    for (int ni = 0; ni < 4; ni++) {
        int n = n0 + wc * 64 + ni * 16 + c;
        float bb = bias[n];
        int h = n >> 6, d = n & 63;
#pragma unroll
        for (int mi = 0; mi < 4; mi++)
#pragma unroll
            for (int j = 0; j < 4; j++) {
                int m = m0 + wr * 64 + mi * 16 + g * 4 + j;
                int b = m >> 11, t = m & 2047;
                float v = acc[mi][ni][j] + bb;
                size_t bhOff = (size_t)(b * 16 + h) * 131072;
                if (z == 0)      Qg[bhOff + (size_t)t * 64 + d] = f2bf(v * QSCALE);
                else if (z == 1) Kg[bhOff + (size_t)t * 64 + d] = f2bf(v);
                else             Vtg[bhOff + (size_t)d * 2048 + t] = f2bf(v);
            }
    }
}

// ---------------------------------------------------------------- flash attention
// Swapped-operand 32x32x16 design: S^T = mfma(K, Q) -> lane owns q-row (col=lane&31);
// O^T = mfma(V^T, P^T) -> (m, l) and rescale lane-local. P^T B-frag built in-register
// via cvt_pk pairs + permlane32_swap (T12). No LDS, no P round-trip.
// grid (16 q-tiles of 128, 64 bh); 256 threads = 4 waves, each wave owns 32 q rows.
__global__ __launch_bounds__(256) void attn_kernel(const uint16_t* __restrict__ Qg,
                                                   const uint16_t* __restrict__ Kg,
                                                   const uint16_t* __restrict__ Vtg,
                                                   uint16_t* __restrict__ Oatt) {
    const int bh = blockIdx.y;
    const int tid = threadIdx.x, wave = tid >> 6, lane = tid & 63;
    const int lo = lane & 31, hi = lane >> 5;
    const int qw = blockIdx.x * 128 + wave * 32;
    const uint16_t* Qb = Qg + (size_t)bh * 131072;
    const uint16_t* Kb = Kg + (size_t)bh * 131072;
    const uint16_t* Vb = Vtg + (size_t)bh * 131072;

    // Q as B-frag of mfma(K,Q): lane holds Q[qw+lo][dc*16 + hi*8 + e]
    bf16x8 qf[4];
#pragma unroll
    for (int dc = 0; dc < 4; dc++)
        qf[dc] = *reinterpret_cast<const bf16x8*>(Qb + (size_t)(qw + lo) * 64 + dc * 16 + hi * 8);

    f32x16 o0, o1;  // O^T accum, dt=0/1: O^T[d=dt*32+(r&3)+8*(r>>2)+4*hi][q=qw+lo]
#pragma unroll
    for (int r = 0; r < 16; r++) { o0[r] = 0.f; o1[r] = 0.f; }
    float m = -__builtin_inff(), l = 0.f;

    for (int kv = 0; kv < 2048; kv += 64) {
        // K as A-frag: K[kv+kt*32+lo][dc*16+hi*8+e]   (contiguous 16B)
        bf16x8 kf[2][4];
#pragma unroll
        for (int kt = 0; kt < 2; kt++)
#pragma unroll
            for (int dc = 0; dc < 4; dc++)
                kf[kt][dc] = *reinterpret_cast<const bf16x8*>(Kb + (size_t)(kv + kt * 32 + lo) * 64 + dc * 16 + hi * 8);
        // V^T as A-frag: Vt[dt*32+lo][kv + kc*16 + hi*8 + e]  (issue early; hides under softmax)
        bf16x8 vf[2][4];
#pragma unroll
        for (int dt = 0; dt < 2; dt++)
#pragma unroll
            for (int kc = 0; kc < 4; kc++)
                vf[dt][kc] = *reinterpret_cast<const bf16x8*>(Vb + (size_t)(dt * 32 + lo) * 2048 + kv + kc * 16 + hi * 8);

        // S^T tiles: p[kt] reg r = S[kv+kt*32+(r&3)+8*(r>>2)+4*hi][qw+lo]
        f32x16 p0, p1;
#pragma unroll
        for (int r = 0; r < 16; r++) { p0[r] = 0.f; p1[r] = 0.f; }
#pragma unroll
        for (int dc = 0; dc < 4; dc++) {
            p0 = __builtin_amdgcn_mfma_f32_32x32x16_bf16(kf[0][dc], qf[dc], p0, 0, 0, 0);
            p1 = __builtin_amdgcn_mfma_f32_32x32x16_bf16(kf[1][dc], qf[dc], p1, 0, 0, 0);
        }

        // Row max: in-lane tree over 32 values + one cross-half exchange.
        float mx[8];
#pragma unroll
        for (int r = 0; r < 8; r++) mx[r] = fmaxf(fmaxf(p0[r], p0[r + 8]), fmaxf(p1[r], p1[r + 8]));
        float pa = fmaxf(fmaxf(mx[0], mx[1]), fmaxf(mx[2], mx[3]));
        float pb = fmaxf(fmaxf(mx[4], mx[5]), fmaxf(mx[6], mx[7]));
        float pm = fmaxf(pa, pb);
        pm = fmaxf(pm, __shfl_xor(pm, 32));

        // Defer-max (T13, THR=8 in exp2 domain): rescale only when max grew past threshold.
        if (!__all(pm <= m + 8.f)) {
            float nm = fmaxf(m, pm);
            float al = __builtin_amdgcn_exp2f(m - nm);
            l *= al;
#pragma unroll
            for (int r = 0; r < 16; r++) { o0[r] *= al; o1[r] *= al; }
            m = nm;
        }

        // P = exp2(S - m); row sum with 4 partial chains.
        float s0 = 0.f, s1 = 0.f, s2 = 0.f, s3 = 0.f;
#pragma unroll
        for (int r = 0; r < 4; r++) {
            p0[r]      = __builtin_amdgcn_exp2f(p0[r] - m);      s0 += p0[r];
            p0[r + 4]  = __builtin_amdgcn_exp2f(p0[r + 4] - m);  s1 += p0[r + 4];
            p0[r + 8]  = __builtin_amdgcn_exp2f(p0[r + 8] - m);  s2 += p0[r + 8];
            p0[r + 12] = __builtin_amdgcn_exp2f(p0[r + 12] - m); s3 += p0[r + 12];
        }
#pragma unroll
        for (int r = 0; r < 4; r++) {
            p1[r]      = __builtin_amdgcn_exp2f(p1[r] - m);      s0 += p1[r];
            p1[r + 4]  = __builtin_amdgcn_exp2f(p1[r + 4] - m);  s1 += p1[r + 4];
            p1[r + 8]  = __builtin_amdgcn_exp2f(p1[r + 8] - m);  s2 += p1[r + 8];
            p1[r + 12] = __builtin_amdgcn_exp2f(p1[r + 12] - m); s3 += p1[r + 12];
        }
        float rs = (s0 + s1) + (s2 + s3);
        rs += __shfl_xor(rs, 32);
        l += rs;

        // Pack P to bf16 pairs: pk[kt][rp] covers k = kt*32 + {4*(rp>>1)+2*(rp&1)... }
        uint32_t pk0[8], pk1[8];
#pragma unroll
        for (int rp = 0; rp < 8; rp++) {
            pk0[rp] = cvtpk(p0[2 * rp], p0[2 * rp + 1]);
            pk1[rp] = cvtpk(p1[2 * rp], p1[2 * rp + 1]);
        }

        // P^T B-frag per 16-k chunk kc: words w0..w3; swap(a,b): res[0]={a.lo,b.lo-half-swapped}
        // gives word w, res[1] gives word w+2.  (If validation fails: flip [0]/[1].)
#pragma unroll
        for (int kc = 0; kc < 4; kc++) {
            const uint32_t* pk = (kc >> 1) ? pk1 : pk0;
            const int b0 = (kc & 1) * 4;
            auto sA = __builtin_amdgcn_permlane32_swap(pk[b0 + 0], pk[b0 + 2], false, false);
            auto sB = __builtin_amdgcn_permlane32_swap(pk[b0 + 1], pk[b0 + 3], false, false);
            bf16x8 pf = __builtin_bit_cast(bf16x8, u32x4{(uint32_t)sA[0], (uint32_t)sB[0],
                                                         (uint32_t)sA[1], (uint32_t)sB[1]});
            o0 = __builtin_amdgcn_mfma_f32_32x32x16_bf16(vf[0][kc], pf, o0, 0, 0, 0);
            o1 = __builtin_amdgcn_mfma_f32_32x32x16_bf16(vf[1][kc], pf, o1, 0, 0, 0);
        }
    }

    // Epilogue: normalize (lane-local l), write O^T -> token-major Oatt[M][C] bf16.
    const int b = bh >> 4, h = bh & 15;
    float inv = 1.0f / l;
    uint16_t* orow = Oatt + (size_t)(b * 2048 + qw + lo) * 1024 + h * 64;
#pragma unroll
    for (int dt = 0; dt < 2; dt++) {
#pragma unroll
        for (int rg = 0; rg < 4; rg++) {
            int dbase = dt * 32 + rg * 8 + hi * 4;
            float v0 = (dt ? o1[rg * 4 + 0] : o0[rg * 4 + 0]) * inv;
            float v1 = (dt ? o1[rg * 4 + 1] : o0[rg * 4 + 1]) * inv;
            float v2 = (dt ? o1[rg * 4 + 2] : o0[rg * 4 + 2]) * inv;
            float v3 = (dt ? o1[rg * 4 + 3] : o0[rg * 4 + 3]) * inv;
            uint2 val;
            val.x = cvtpk(v0, v1);
            val.y = cvtpk(v2, v3);
            *reinterpret_cast<uint2*>(orow + dbase) = val;
        }
    }
}

// ---------------------------------------------------------------- output projection (f32 out)
__global__ __launch_bounds__(256) void out_gemm_kernel(const uint16_t* __restrict__ Oatt,
                                                       const uint16_t* __restrict__ WtO,
                                                       const float* __restrict__ bo,
                                                       float* __restrict__ out) {
    __shared__ uint16_t Als[4096], Bls[4096];
    const int m0 = blockIdx.y * 128, n0 = blockIdx.x * 128;
    f32x4 acc[4][4];
    gemm128_mainloop(Oatt, WtO, m0, n0, Als, Bls, acc);

    const int tid = threadIdx.x, wave = tid >> 6, lane = tid & 63;
    const int g = lane >> 4, c = lane & 15;
    const int wr = wave >> 1, wc = wave & 1;
#pragma unroll
    for (int ni = 0; ni < 4; ni++) {
        int n = n0 + wc * 64 + ni * 16 + c;
        float bb = bo[n];
#pragma unroll
        for (int mi = 0; mi < 4; mi++)
#pragma unroll
            for (int j = 0; j < 4; j++) {
                int m = m0 + wr * 64 + mi * 16 + g * 4 + j;
                out[(size_t)m * 1024 + n] = acc[mi][ni][j] + bb;
            }
    }
}

// ---------------------------------------------------------------- launch
extern "C" void kernel_launch(void* const* d_in, const int* in_sizes, int n_in,
                              void* d_out, int out_size, void* d_ws, size_t ws_size,
                              hipStream_t stream) {
    const float* x  = (const float*)d_in[0];
    const float* Wq = (const float*)d_in[1];
    const float* bq = (const float*)d_in[2];
    const float* Wk = (const float*)d_in[3];
    const float* bk = (const float*)d_in[4];
    const float* Wv = (const float*)d_in[5];
    const float* bv = (const float*)d_in[6];
    const float* Wo = (const float*)d_in[7];
    const float* bo = (const float*)d_in[8];
    float* out = (float*)d_out;

    char* ws = (char*)d_ws;
    uint16_t* xb   = (uint16_t*)(ws);
    uint16_t* Wt   = (uint16_t*)(ws + 16777216);
    uint16_t* Qg   = (uint16_t*)(ws + 25165824);
    uint16_t* Kg   = (uint16_t*)(ws + 41943040);
    uint16_t* Vtg  = (uint16_t*)(ws + 58720256);
    uint16_t* Oatt = (uint16_t*)(ws);  // reuse xb region (xb dead after qkv_gemm)

    convert_x_kernel<<<4096, 256, 0, stream>>>(x, xb, MTOK * CDIM);
    transpose_w_kernel<<<dim3(32, 32, 4), dim3(32, 8), 0, stream>>>(Wq, Wk, Wv, Wo, Wt);
    qkv_gemm_kernel<<<dim3(8, 64, 3), 256, 0, stream>>>(xb, Wt, bq, bk, bv, Qg, Kg, Vtg);
    attn_kernel<<<dim3(16, 64), 256, 0, stream>>>(Qg, Kg, Vtg, Oatt);
    out_gemm_kernel<<<dim3(8, 64), 256, 0, stream>>>(Oatt, Wt + (size_t)3 * 1048576, bo, out);
}

// Round 9
// 320.404 us; speedup vs baseline: 1.5800x; 1.4080x over previous
//
#include <hip/hip_runtime.h>
#include <cstdint>
#include <cstddef>

// Problem constants: B=4, T=2048, C=1024, H=16, D=64, tokens M=8192.
#define MTOK 8192
#define CDIM 1024

typedef __bf16 bf16x8 __attribute__((ext_vector_type(8)));
typedef float  f32x4  __attribute__((ext_vector_type(4)));
typedef float  f32x16 __attribute__((ext_vector_type(16)));
typedef uint32_t u32x4 __attribute__((ext_vector_type(4)));

// 1/sqrt(64) * log2(e): QK^T softmax done in exp2 domain.
#define QSCALE 0.18033688011112042f

__device__ __forceinline__ uint16_t f2bf(float f) {
    return __builtin_bit_cast(uint16_t, (__bf16)f);  // HW RNE cvt (don't hand-write; m240)
}
__device__ __forceinline__ uint32_t cvtpk(float lo, float hi) {
    return (uint32_t)__builtin_bit_cast(uint16_t, (__bf16)lo) |
           ((uint32_t)__builtin_bit_cast(uint16_t, (__bf16)hi) << 16);
}

__device__ __forceinline__ void gload_lds16(const uint16_t* g, uint16_t* l) {
    __builtin_amdgcn_global_load_lds((const __attribute__((address_space(1))) void*)g,
                                     (__attribute__((address_space(3))) void*)l, 16, 0, 0);
}

// ---------------------------------------------------------------- prep kernels
__global__ __launch_bounds__(256) void convert_x_kernel(const float* __restrict__ x,
                                                        uint16_t* __restrict__ xb, int n) {
    int i = (blockIdx.x * 256 + threadIdx.x) * 4;
    int stride = gridDim.x * 256 * 4;
    for (; i < n; i += stride) {
        float4 v = *reinterpret_cast<const float4*>(x + i);
        uint64_t pk = (uint64_t)cvtpk(v.x, v.y) | ((uint64_t)cvtpk(v.z, v.w) << 32);
        *reinterpret_cast<uint64_t*>(xb + i) = pk;
    }
}

// W[k][n] f32  ->  Wt[n][k] bf16   (4 weights via blockIdx.z)
__global__ __launch_bounds__(256) void transpose_w_kernel(const float* __restrict__ W0,
                                                          const float* __restrict__ W1,
                                                          const float* __restrict__ W2,
                                                          const float* __restrict__ W3,
                                                          uint16_t* __restrict__ Wt) {
    __shared__ float tile[32][33];
    const float* W = blockIdx.z == 0 ? W0 : blockIdx.z == 1 ? W1 : blockIdx.z == 2 ? W2 : W3;
    uint16_t* out = Wt + (size_t)blockIdx.z * 1024 * 1024;
    int k0 = blockIdx.y * 32, n0 = blockIdx.x * 32;
    int tx = threadIdx.x, ty = threadIdx.y;  // block (32,8)
#pragma unroll
    for (int i = 0; i < 4; i++) tile[ty * 4 + i][tx] = W[(size_t)(k0 + ty * 4 + i) * 1024 + n0 + tx];
    __syncthreads();
#pragma unroll
    for (int i = 0; i < 4; i++) out[(size_t)(n0 + ty * 4 + i) * 1024 + k0 + tx] = f2bf(tile[tx][ty * 4 + i]);
}

// ---------------------------------------------------------------- GEMM mainloop
__device__ __forceinline__ void gemm128_mainloop(const uint16_t* __restrict__ A,
                                                 const uint16_t* __restrict__ Wt,
                                                 int m0, int n0,
                                                 uint16_t* Als, uint16_t* Bls,
                                                 f32x4 acc[4][4]) {
    const int tid = threadIdx.x;
    const int wave = tid >> 6, lane = tid & 63;
    const int g = lane >> 4, c = lane & 15;
    const int wr = wave >> 1, wc = wave & 1;
    const int r = tid >> 2, cc = (tid & 3) * 8;
#pragma unroll
    for (int mi = 0; mi < 4; mi++)
#pragma unroll
        for (int ni = 0; ni < 4; ni++) acc[mi][ni] = f32x4{0.f, 0.f, 0.f, 0.f};

    for (int k0 = 0; k0 < 1024; k0 += 32) {
        __syncthreads();
        gload_lds16(A + (size_t)(m0 + r) * 1024 + k0 + cc, Als + wave * 512);
        gload_lds16(A + (size_t)(m0 + 64 + r) * 1024 + k0 + cc, Als + 2048 + wave * 512);
        gload_lds16(Wt + (size_t)(n0 + r) * 1024 + k0 + cc, Bls + wave * 512);
        gload_lds16(Wt + (size_t)(n0 + 64 + r) * 1024 + k0 + cc, Bls + 2048 + wave * 512);
        __syncthreads();
        bf16x8 af[4], bf[4];
#pragma unroll
        for (int mi = 0; mi < 4; mi++)
            af[mi] = *reinterpret_cast<const bf16x8*>(Als + (wr * 64 + mi * 16 + c) * 32 + g * 8);
#pragma unroll
        for (int ni = 0; ni < 4; ni++)
            bf[ni] = *reinterpret_cast<const bf16x8*>(Bls + (wc * 64 + ni * 16 + c) * 32 + g * 8);
#pragma unroll
        for (int mi = 0; mi < 4; mi++)
#pragma unroll
            for (int ni = 0; ni < 4; ni++)
                acc[mi][ni] = __builtin_amdgcn_mfma_f32_16x16x32_bf16(af[mi], bf[ni], acc[mi][ni], 0, 0, 0);
    }
}

// ---------------------------------------------------------------- QKV projection
// z=0: Q = (x@Wq+bq)*QSCALE -> [B,H,T,D] bf16 (attn scale + log2e folded)
// z=1: K = x@Wk+bk          -> [B,H,T,D] bf16
// z=2: V = x@Wv+bv          -> [B,H,D,T] bf16 (transposed: PV/O^T A-frag reads)
__global__ __launch_bounds__(256) void qkv_gemm_kernel(const uint16_t* __restrict__ xb,
                                                       const uint16_t* __restrict__ WtAll,
                                                       const float* __restrict__ bq,
                                                       const float* __restrict__ bk,
                                                       const float* __restrict__ bv,
                                                       uint16_t* __restrict__ Qg,
                                                       uint16_t* __restrict__ Kg,
                                                       uint16_t* __restrict__ Vtg) {
    __shared__ uint16_t Als[4096], Bls[4096];
    const int z = blockIdx.z;
    const uint16_t* Wt = WtAll + (size_t)z * 1024 * 1024;
    const float* bias = z == 0 ? bq : z == 1 ? bk : bv;
    const int m0 = blockIdx.y * 128, n0 = blockIdx.x * 128;
    f32x4 acc[4][4];
    gemm128_mainloop(xb, Wt, m0, n0, Als, Bls, acc);

    const int tid = threadIdx.x, wave = tid >> 6, lane = tid & 63;
    const int g = lane >> 4, c = lane & 15;
    const int wr = wave >> 1, wc = wave & 1;
#pragma unroll
    for (int ni = 0; ni < 4; ni++) {
        int n = n0 + wc * 64 + ni * 16 + c;
        float bb = bias[n];
        int h = n >> 6, d = n & 63;
#pragma unroll
        for (int mi = 0; mi < 4; mi++)
#pragma unroll
            for (int j = 0; j < 4; j++) {
                int m = m0 + wr * 64 + mi * 16 + g * 4 + j;
                int b = m >> 11, t = m & 2047;
                float v = acc[mi][ni][j] + bb;
                size_t bhOff = (size_t)(b * 16 + h) * 131072;
                if (z == 0)      Qg[bhOff + (size_t)t * 64 + d] = f2bf(v * QSCALE);
                else if (z == 1) Kg[bhOff + (size_t)t * 64 + d] = f2bf(v);
                else             Vtg[bhOff + (size_t)d * 2048 + t] = f2bf(v);
            }
    }
}

// ---------------------------------------------------------------- flash attention
// 8-wave m214-style structure: K and V^T tiles (64 kv x 64 d / 64 d x 64 kv) staged
// in LDS via global_load_lds (linear dest + inverse-XOR-swizzled per-lane SOURCE,
// rule 21), double-buffered, one barrier per kv-step (T3 minimum 2-phase).
// Swapped-operand 32x32x16: S^T = mfma(K,Q), O^T = mfma(V^T,P^T); softmax lane-local;
// P^T built in-register via cvt_pk + permlane32_swap (T12); defer-max (T13).
// XCD-bijective swizzle: the 8 q-blocks of each bh land on one XCD -> K/V L2-resident.
__global__ __launch_bounds__(512, 4) void attn_kernel(const uint16_t* __restrict__ Qg,
                                                      const uint16_t* __restrict__ Kg,
                                                      const uint16_t* __restrict__ Vtg,
                                                      uint16_t* __restrict__ Oatt) {
    const int blk = blockIdx.x;                 // 512 blocks
    const int xcd = blk & 7, j = blk >> 3;      // consecutive blocks round-robin XCDs
    const int bh = xcd * 8 + (j >> 3);          // 8 bh per XCD, 8 q-blocks per bh
    const int q0 = (j & 7) * 256;

    const int tid = threadIdx.x, wave = tid >> 6, lane = tid & 63;
    const int lo = lane & 31, hi = lane >> 5, lo7 = lo & 7;
    const int qw = q0 + wave * 32;
    const uint16_t* Qb = Qg + (size_t)bh * 131072;
    const uint16_t* Kb = Kg + (size_t)bh * 131072;
    const uint16_t* Vb = Vtg + (size_t)bh * 131072;

    __shared__ __align__(16) uint16_t Kls[2][4096];  // [buf][64 rows x 64 elem], 8KB each
    __shared__ __align__(16) uint16_t Vls[2][4096];

    // Staging geometry: wave w covers tile rows [w*8, w*8+8); lane l -> LDS slot
    // (r = w*8 + l/8, slot-chunk c' = l%8). Slot holds logical chunk c'^(r&7), so the
    // per-lane GLOBAL source is pre-swizzled: chunk sc = (l&7)^((l/8)&7).
    const int sr = lane >> 3;
    const int sc = (lane & 7) ^ (sr & 7);
    const int w8 = wave * 8;

    // Q as B-frag of mfma(K,Q): lane holds Q[qw+lo][dc*16 + hi*8 + e]
    bf16x8 qf[4];
#pragma unroll
    for (int dc = 0; dc < 4; dc++)
        qf[dc] = *reinterpret_cast<const bf16x8*>(Qb + (size_t)(qw + lo) * 64 + dc * 16 + hi * 8);

    f32x16 o0, o1;  // O^T accum, dt=0/1: O^T[d=dt*32+(r&3)+8*(r>>2)+4*hi][q=qw+lo]
#pragma unroll
    for (int r = 0; r < 16; r++) { o0[r] = 0.f; o1[r] = 0.f; }
    float m = -__builtin_inff(), l = 0.f;

    // Prologue: stage kv-tile 0 into buf 0.
    gload_lds16(Kb + (size_t)(w8 + sr) * 64 + sc * 8, &Kls[0][wave * 512]);
    gload_lds16(Vb + (size_t)(w8 + sr) * 2048 + sc * 8, &Vls[0][wave * 512]);
    __syncthreads();  // drains vmcnt: tile 0 resident

    for (int t = 0; t < 32; ++t) {
        const int cur = t & 1;
        const uint16_t* Kc = Kls[cur];
        const uint16_t* Vc = Vls[cur];
        // Issue next tile's staging first; its latency hides under this step's compute.
        if (t < 31) {
            const int kvn = (t + 1) * 64;
            gload_lds16(Kb + (size_t)(kvn + w8 + sr) * 64 + sc * 8, &Kls[cur ^ 1][wave * 512]);
            gload_lds16(Vb + (size_t)(w8 + sr) * 2048 + kvn + sc * 8, &Vls[cur ^ 1][wave * 512]);
        }

        // --- S^T = mfma(K, Q). ds_read row r=kt*32+lo, chunk (dc*2+hi)^(r&7) [T2 swizzle].
        f32x16 p0, p1;
#pragma unroll
        for (int r = 0; r < 16; r++) { p0[r] = 0.f; p1[r] = 0.f; }
        {
            const uint16_t* base = Kc + lo * 64;
            bf16x8 ka = *reinterpret_cast<const bf16x8*>(base + (((0 + hi) ^ lo7) * 8));
            bf16x8 kb2 = *reinterpret_cast<const bf16x8*>(base + (((2 + hi) ^ lo7) * 8));
            bf16x8 kc2 = *reinterpret_cast<const bf16x8*>(base + (((4 + hi) ^ lo7) * 8));
            bf16x8 kd = *reinterpret_cast<const bf16x8*>(base + (((6 + hi) ^ lo7) * 8));
            __builtin_amdgcn_s_setprio(1);
            p0 = __builtin_amdgcn_mfma_f32_32x32x16_bf16(ka, qf[0], p0, 0, 0, 0);
            p0 = __builtin_amdgcn_mfma_f32_32x32x16_bf16(kb2, qf[1], p0, 0, 0, 0);
            p0 = __builtin_amdgcn_mfma_f32_32x32x16_bf16(kc2, qf[2], p0, 0, 0, 0);
            p0 = __builtin_amdgcn_mfma_f32_32x32x16_bf16(kd, qf[3], p0, 0, 0, 0);
            __builtin_amdgcn_s_setprio(0);
        }
        {
            const uint16_t* base = Kc + (32 + lo) * 64;
            bf16x8 ka = *reinterpret_cast<const bf16x8*>(base + (((0 + hi) ^ lo7) * 8));
            bf16x8 kb2 = *reinterpret_cast<const bf16x8*>(base + (((2 + hi) ^ lo7) * 8));
            bf16x8 kc2 = *reinterpret_cast<const bf16x8*>(base + (((4 + hi) ^ lo7) * 8));
            bf16x8 kd = *reinterpret_cast<const bf16x8*>(base + (((6 + hi) ^ lo7) * 8));
            __builtin_amdgcn_s_setprio(1);
            p1 = __builtin_amdgcn_mfma_f32_32x32x16_bf16(ka, qf[0], p1, 0, 0, 0);
            p1 = __builtin_amdgcn_mfma_f32_32x32x16_bf16(kb2, qf[1], p1, 0, 0, 0);
            p1 = __builtin_amdgcn_mfma_f32_32x32x16_bf16(kc2, qf[2], p1, 0, 0, 0);
            p1 = __builtin_amdgcn_mfma_f32_32x32x16_bf16(kd, qf[3], p1, 0, 0, 0);
            __builtin_amdgcn_s_setprio(0);
        }

        // --- Online softmax (lane owns q-row qw+lo). In-lane tree + one cross-half swap.
        float mx[8];
#pragma unroll
        for (int r = 0; r < 8; r++) mx[r] = fmaxf(fmaxf(p0[r], p0[r + 8]), fmaxf(p1[r], p1[r + 8]));
        float pa = fmaxf(fmaxf(mx[0], mx[1]), fmaxf(mx[2], mx[3]));
        float pb = fmaxf(fmaxf(mx[4], mx[5]), fmaxf(mx[6], mx[7]));
        float pm = fmaxf(pa, pb);
        pm = fmaxf(pm, __shfl_xor(pm, 32));

        // Defer-max (T13, THR=8 in exp2 domain).
        if (!__all(pm <= m + 8.f)) {
            float nm = fmaxf(m, pm);
            float al = __builtin_amdgcn_exp2f(m - nm);
            l *= al;
#pragma unroll
            for (int r = 0; r < 16; r++) { o0[r] *= al; o1[r] *= al; }
            m = nm;
        }

        float s0 = 0.f, s1 = 0.f, s2 = 0.f, s3 = 0.f;
#pragma unroll
        for (int r = 0; r < 4; r++) {
            p0[r]      = __builtin_amdgcn_exp2f(p0[r] - m);      s0 += p0[r];
            p0[r + 4]  = __builtin_amdgcn_exp2f(p0[r + 4] - m);  s1 += p0[r + 4];
            p0[r + 8]  = __builtin_amdgcn_exp2f(p0[r + 8] - m);  s2 += p0[r + 8];
            p0[r + 12] = __builtin_amdgcn_exp2f(p0[r + 12] - m); s3 += p0[r + 12];
        }
#pragma unroll
        for (int r = 0; r < 4; r++) {
            p1[r]      = __builtin_amdgcn_exp2f(p1[r] - m);      s0 += p1[r];
            p1[r + 4]  = __builtin_amdgcn_exp2f(p1[r + 4] - m);  s1 += p1[r + 4];
            p1[r + 8]  = __builtin_amdgcn_exp2f(p1[r + 8] - m);  s2 += p1[r + 8];
            p1[r + 12] = __builtin_amdgcn_exp2f(p1[r + 12] - m); s3 += p1[r + 12];
        }
        float rs = (s0 + s1) + (s2 + s3);
        rs += __shfl_xor(rs, 32);
        l += rs;

        // --- Pack P to bf16 + permlane32_swap -> P^T B-frags (T12), fully in-register.
        uint32_t pk0[8], pk1[8];
#pragma unroll
        for (int rp = 0; rp < 8; rp++) {
            pk0[rp] = cvtpk(p0[2 * rp], p0[2 * rp + 1]);
            pk1[rp] = cvtpk(p1[2 * rp], p1[2 * rp + 1]);
        }
        bf16x8 pf[4];
#pragma unroll
        for (int kc = 0; kc < 4; kc++) {
            const uint32_t* pk = (kc >> 1) ? pk1 : pk0;
            const int b0 = (kc & 1) * 4;
            auto sA = __builtin_amdgcn_permlane32_swap(pk[b0 + 0], pk[b0 + 2], false, false);
            auto sB = __builtin_amdgcn_permlane32_swap(pk[b0 + 1], pk[b0 + 3], false, false);
            pf[kc] = __builtin_bit_cast(bf16x8, u32x4{(uint32_t)sA[0], (uint32_t)sB[0],
                                                      (uint32_t)sA[1], (uint32_t)sB[1]});
        }

        // --- O^T += mfma(V^T, P^T). V^T rows d=dt*32+lo, chunk (kc*2+hi)^(d&7).
        {
            const uint16_t* base = Vc + lo * 64;
            bf16x8 va = *reinterpret_cast<const bf16x8*>(base + (((0 + hi) ^ lo7) * 8));
            bf16x8 vb2 = *reinterpret_cast<const bf16x8*>(base + (((2 + hi) ^ lo7) * 8));
            bf16x8 vc2 = *reinterpret_cast<const bf16x8*>(base + (((4 + hi) ^ lo7) * 8));
            bf16x8 vd = *reinterpret_cast<const bf16x8*>(base + (((6 + hi) ^ lo7) * 8));
            __builtin_amdgcn_s_setprio(1);
            o0 = __builtin_amdgcn_mfma_f32_32x32x16_bf16(va, pf[0], o0, 0, 0, 0);
            o0 = __builtin_amdgcn_mfma_f32_32x32x16_bf16(vb2, pf[1], o0, 0, 0, 0);
            o0 = __builtin_amdgcn_mfma_f32_32x32x16_bf16(vc2, pf[2], o0, 0, 0, 0);
            o0 = __builtin_amdgcn_mfma_f32_32x32x16_bf16(vd, pf[3], o0, 0, 0, 0);
            __builtin_amdgcn_s_setprio(0);
        }
        {
            const uint16_t* base = Vc + (32 + lo) * 64;
            bf16x8 va = *reinterpret_cast<const bf16x8*>(base + (((0 + hi) ^ lo7) * 8));
            bf16x8 vb2 = *reinterpret_cast<const bf16x8*>(base + (((2 + hi) ^ lo7) * 8));
            bf16x8 vc2 = *reinterpret_cast<const bf16x8*>(base + (((4 + hi) ^ lo7) * 8));
            bf16x8 vd = *reinterpret_cast<const bf16x8*>(base + (((6 + hi) ^ lo7) * 8));
            __builtin_amdgcn_s_setprio(1);
            o1 = __builtin_amdgcn_mfma_f32_32x32x16_bf16(va, pf[0], o1, 0, 0, 0);
            o1 = __builtin_amdgcn_mfma_f32_32x32x16_bf16(vb2, pf[1], o1, 0, 0, 0);
            o1 = __builtin_amdgcn_mfma_f32_32x32x16_bf16(vc2, pf[2], o1, 0, 0, 0);
            o1 = __builtin_amdgcn_mfma_f32_32x32x16_bf16(vd, pf[3], o1, 0, 0, 0);
            __builtin_amdgcn_s_setprio(0);
        }

        // One barrier per step: drains next-tile staging (vmcnt) and this step's
        // ds_reads (lgkm) before buffers flip.
        __syncthreads();
    }

    // Epilogue: normalize (lane-local l), write O^T -> token-major Oatt[M][C] bf16.
    const int b = bh >> 4, h = bh & 15;
    float inv = 1.0f / l;
    uint16_t* orow = Oatt + (size_t)(b * 2048 + qw + lo) * 1024 + h * 64;
#pragma unroll
    for (int dt = 0; dt < 2; dt++) {
#pragma unroll
        for (int rg = 0; rg < 4; rg++) {
            int dbase = dt * 32 + rg * 8 + hi * 4;
            float v0 = (dt ? o1[rg * 4 + 0] : o0[rg * 4 + 0]) * inv;
            float v1 = (dt ? o1[rg * 4 + 1] : o0[rg * 4 + 1]) * inv;
            float v2 = (dt ? o1[rg * 4 + 2] : o0[rg * 4 + 2]) * inv;
            float v3 = (dt ? o1[rg * 4 + 3] : o0[rg * 4 + 3]) * inv;
            uint2 val;
            val.x = cvtpk(v0, v1);
            val.y = cvtpk(v2, v3);
            *reinterpret_cast<uint2*>(orow + dbase) = val;
        }
    }
}

// ---------------------------------------------------------------- output projection (f32 out)
__global__ __launch_bounds__(256) void out_gemm_kernel(const uint16_t* __restrict__ Oatt,
                                                       const uint16_t* __restrict__ WtO,
                                                       const float* __restrict__ bo,
                                                       float* __restrict__ out) {
    __shared__ uint16_t Als[4096], Bls[4096];
    const int m0 = blockIdx.y * 128, n0 = blockIdx.x * 128;
    f32x4 acc[4][4];
    gemm128_mainloop(Oatt, WtO, m0, n0, Als, Bls, acc);

    const int tid = threadIdx.x, wave = tid >> 6, lane = tid & 63;
    const int g = lane >> 4, c = lane & 15;
    const int wr = wave >> 1, wc = wave & 1;
#pragma unroll
    for (int ni = 0; ni < 4; ni++) {
        int n = n0 + wc * 64 + ni * 16 + c;
        float bb = bo[n];
#pragma unroll
        for (int mi = 0; mi < 4; mi++)
#pragma unroll
            for (int j = 0; j < 4; j++) {
                int m = m0 + wr * 64 + mi * 16 + g * 4 + j;
                out[(size_t)m * 1024 + n] = acc[mi][ni][j] + bb;
            }
    }
}

// ---------------------------------------------------------------- launch
extern "C" void kernel_launch(void* const* d_in, const int* in_sizes, int n_in,
                              void* d_out, int out_size, void* d_ws, size_t ws_size,
                              hipStream_t stream) {
    const float* x  = (const float*)d_in[0];
    const float* Wq = (const float*)d_in[1];
    const float* bq = (const float*)d_in[2];
    const float* Wk = (const float*)d_in[3];
    const float* bk = (const float*)d_in[4];
    const float* Wv = (const float*)d_in[5];
    const float* bv = (const float*)d_in[6];
    const float* Wo = (const float*)d_in[7];
    const float* bo = (const float*)d_in[8];
    float* out = (float*)d_out;

    char* ws = (char*)d_ws;
    uint16_t* xb   = (uint16_t*)(ws);
    uint16_t* Wt   = (uint16_t*)(ws + 16777216);
    uint16_t* Qg   = (uint16_t*)(ws + 25165824);
    uint16_t* Kg   = (uint16_t*)(ws + 41943040);
    uint16_t* Vtg  = (uint16_t*)(ws + 58720256);
    uint16_t* Oatt = (uint16_t*)(ws);  // reuse xb region (xb dead after qkv_gemm)

    convert_x_kernel<<<4096, 256, 0, stream>>>(x, xb, MTOK * CDIM);
    transpose_w_kernel<<<dim3(32, 32, 4), dim3(32, 8), 0, stream>>>(Wq, Wk, Wv, Wo, Wt);
    qkv_gemm_kernel<<<dim3(8, 64, 3), 256, 0, stream>>>(xb, Wt, bq, bk, bv, Qg, Kg, Vtg);
    attn_kernel<<<512, 512, 0, stream>>>(Qg, Kg, Vtg, Oatt);
    out_gemm_kernel<<<dim3(8, 64), 256, 0, stream>>>(Oatt, Wt + (size_t)3 * 1048576, bo, out);
}